// Round 4
// baseline (862.959 us; speedup 1.0000x reference)
//
#include <hip/hip_runtime.h>
#include <hip/hip_bf16.h>
#include <cstdint>
#include <cstddef>

// QRNN (window=2) fused: f16 MFMA GEMM for gates + epilogue activations +
// sequence-parallel diagonal-recurrence scan.
//
// R1: XOR-swizzled LDS (bank conflicts -> 0). GEMM 605->440us.
// R2: 3-phase sequence-parallel scan (chunk reduce/scan/apply).
// R3/R4: 256^2 8-phase schedule, counted vmcnt. REGRESSED (527us, MfmaUtil 35%):
//     per-phase staging put the end-of-tile vmcnt(2) only ~1.5 phases after the
//     B1 issue -> all 8 waves stall on a just-issued load every K-tile.
// R5: issue ALL 8 next-tile gl_lds at top of P0 (Ae,B0,B1,Ao order).
//     Waits now target loads >=3.5 phases old: P1 vmcnt(8) drains Ao(t)
//     (5-phase cover), P3 vmcnt(2) drains Ae/B0/B1(t+1) (3.5-phase cover),
//     Ao(t+1) never force-drained in-loop. Everything else unchanged.
// R6: resubmission of R5 — previous round failed with GPUAcquisitionTimeout
//     (broker capacity), no measurement was taken.

typedef _Float16 f16;
typedef _Float16 f16x2 __attribute__((ext_vector_type(2)));
typedef _Float16 f16x4 __attribute__((ext_vector_type(4)));
typedef _Float16 f16x8 __attribute__((ext_vector_type(8)));
typedef float f32x4 __attribute__((ext_vector_type(4)));

#define Bb 16
#define Ss 2048
#define Dd 1024
#define Hh 1024
#define Nn (3 * Hh)   // 3072
#define Kk (2 * Dd)   // 2048
#define BH (Bb * Hh)  // 16384
#define NCH 16        // scan chunks
#define CL 128        // chunk length = Ss/NCH
#define NQ 8192       // chain pairs = BH/2
#define NT 32         // GEMM K-tiles (2048/64)

#define BAR() do { asm volatile("" ::: "memory"); __builtin_amdgcn_s_barrier(); asm volatile("" ::: "memory"); } while (0)
#define LGKM0() asm volatile("s_waitcnt lgkmcnt(0)" ::: "memory")
#define VMW(n) asm volatile("s_waitcnt vmcnt(" #n ")" ::: "memory")

__device__ __forceinline__ void gl_lds16(const void* g, void* l) {
  __builtin_amdgcn_global_load_lds(
      (const __attribute__((address_space(1))) void*)g,
      (__attribute__((address_space(3))) void*)l, 16, 0, 0);
}

__global__ void cvt_f32_f16(const float* __restrict__ in, f16* __restrict__ out, int n4) {
  int i = blockIdx.x * blockDim.x + threadIdx.x;
  if (i < n4) {
    const float4 v = ((const float4*)in)[i];
    f16x4 h;
    h[0] = (f16)v.x; h[1] = (f16)v.y; h[2] = (f16)v.z; h[3] = (f16)v.w;
    ((f16x4*)out)[i] = h;
  }
}

// Read 4 MFMA fragments (f16x8 each) from a swizzled [256][64] f16 LDS tile.
// Stored layout: row r, segment slot p (16B) holds global k-segment p ^ (r&7).
__device__ __forceinline__ void read4(const f16* __restrict__ P, int rbase, int kkv,
                                      int r, int q, f16x8 fr[4]) {
#pragma unroll
  for (int i = 0; i < 4; ++i) {
    const int row = rbase + i * 16 + r;
    const int seg = ((kkv >> 3) + q) ^ (row & 7);
    fr[i] = *(const f16x8*)(P + row * 64 + seg * 8);
  }
}

__device__ __forceinline__ void mfma16(const f16x8 af[4], const f16x8 bf[4],
                                       f32x4 (*acc)[4]) {
#pragma unroll
  for (int mi = 0; mi < 4; ++mi)
#pragma unroll
    for (int ni = 0; ni < 4; ++ni)
      acc[mi][ni] = __builtin_amdgcn_mfma_f32_16x16x32_f16(af[mi], bf[ni], acc[mi][ni], 0, 0, 0);
}

// 256x256 tile, BK=64, 512 threads (8 waves as 2Mx4N, each 128x64 output).
// A is the gathered window-concat of Xh; B is Wh [n][k] row-major (B^T natural).
// Requires 4KiB of zeros immediately BEFORE Xh (s==0 shifted reads land there).
__global__ __launch_bounds__(512, 2)
void gemm_gates(const f16* __restrict__ Xh,    // (B,S,D) f16, zeros at Xh[-2048..-1]
                const f16* __restrict__ Wh,    // (3H,2D) f16
                const float* __restrict__ bias,// (3H)
                f16* __restrict__ Zg, f16* __restrict__ Fg, f16* __restrict__ Og) {
  __shared__ __align__(16) f16 As[2][256 * 64];  // 64 KiB
  __shared__ __align__(16) f16 Bs[2][256 * 64];  // 64 KiB

  const int tid  = threadIdx.x;
  const int wave = tid >> 6;      // 0..7
  const int lane = tid & 63;

  // XCD-bijective swizzle: 1536 blocks, 1536/8 = 192 per XCD chunk, n-fast.
  const int bid = blockIdx.x;
  const int v = (bid & 7) * 192 + (bid >> 3);
  const int bm = v / 12, bn = v - bm * 12;
  const int m0 = bm << 8, n0 = bn << 8;

  const int wmBase = (wave >> 2) * 128;   // wave's A-row base in tile
  const int wnBase = (wave & 3) * 64;     // wave's B-row (n-col) base in tile
  const int r = lane & 15, q = lane >> 4;

  // Staging: per gl_lds a wave fills 8 rows x 64 k (1024B linear LDS).
  // lane -> row = trow0 + lane/8, seg-slot = lane&7; source seg = slot ^ (row&7).
  const int srl   = lane >> 3;
  const int sseg8 = ((lane & 7) ^ srl) * 8;   // swizzled k-elem offset

  // Per-thread staging offsets (elems, relative to Xh / Wh) and LDS dests.
  // Half-tiles: Ae = rows {0-63,128-191} (read phases 0-1),
  //             Ao = rows {64-127,192-255} (read phases 2-3),
  //             B0 = n-rows 0-127, B1 = 128-255 (both read every phase).
  int oAeC[2], oAeP[2], oAoC[2], oAoP[2], oB0[2], oB1[2];
  int dAe[2], dAo[2], dB0[2], dB1[2];
#pragma unroll
  for (int j = 0; j < 2; ++j) {
    const int idx = wave * 2 + j;                       // 0..15 chunk id
    const int t0e = ((idx & 8) << 4) + ((idx & 7) << 3); // Ae chunk row0
    dAe[j] = t0e * 64;
    dAo[j] = dAe[j] + 4096;        // +64 rows
    dB0[j] = idx * 512;            // idx*8 rows
    dB1[j] = dB0[j] + 8192;        // +128 rows
    const int m = m0 + t0e + srl;  // global M row (= s*16 + b)
    const int s = m >> 4, b = m & 15;
    oAeC[j] = b * (Ss * Dd) + s * Dd + sseg8;                    // k < 1024 path
    oAeP[j] = (s > 0) ? (oAeC[j] - Dd - 1024)                    // k >= 1024: X[s-1]
                      : (sseg8 - 3072);                          // s==0: zero pad
    oAoC[j] = oAeC[j] + 4 * Dd;        // rows +64 -> s+4
    oAoP[j] = oAeC[j] + 3 * Dd - 1024; // (s+4)-1 = s+3, always valid
    const int n = n0 + idx * 8 + srl;
    oB0[j] = n * Kk + sseg8;
    oB1[j] = oB0[j] + 128 * Kk;
  }

  f32x4 acc[8][4];
#pragma unroll
  for (int i = 0; i < 8; ++i)
#pragma unroll
    for (int j = 0; j < 4; ++j)
      acc[i][j] = {0.f, 0.f, 0.f, 0.f};

  // Prologue: stage tile 0 (issue order Ae,B0,B1,Ao), wait to 2 (Ao may fly).
  {
    f16* An = (f16*)As[0]; f16* Bn = (f16*)Bs[0];
    gl_lds16(Xh + oAeC[0], An + dAe[0]);
    gl_lds16(Xh + oAeC[1], An + dAe[1]);
    gl_lds16(Wh + oB0[0],  Bn + dB0[0]);
    gl_lds16(Wh + oB0[1],  Bn + dB0[1]);
    gl_lds16(Wh + oB1[0],  Bn + dB1[0]);
    gl_lds16(Wh + oB1[1],  Bn + dB1[1]);
    gl_lds16(Xh + oAoC[0], An + dAo[0]);
    gl_lds16(Xh + oAoC[1], An + dAo[1]);
  }
  VMW(2);
  BAR();

#pragma unroll 1
  for (int t = 0; t < NT - 1; ++t) {
    const f16* Ac = As[t & 1];
    const f16* Bc = Bs[t & 1];
    f16* An = (f16*)As[(t & 1) ^ 1];
    f16* Bn = (f16*)Bs[(t & 1) ^ 1];
    const int kf2 = (t + 1) << 6;   // k base of the tile being staged
    int ae0, ae1, ao0, ao1;
    if (kf2 < 1024) {               // uniform branch (kf2 uniform)
      ae0 = oAeC[0] + kf2; ae1 = oAeC[1] + kf2;
      ao0 = oAoC[0] + kf2; ao1 = oAoC[1] + kf2;
    } else {
      ae0 = oAeP[0] + kf2; ae1 = oAeP[1] + kf2;
      ao0 = oAoP[0] + kf2; ao1 = oAoP[1] + kf2;
    }
    f16x8 af[4], bf0[4], bf1[4];

    // P0: issue ALL of tile t+1's staging (Ae,B0,B1 first, Ao last), then
    //     read A(mi0-3,kk0)+B(kk0), MFMA. Waits for these loads happen 3.5-5
    //     phases from now — never on a just-issued load.
    gl_lds16(Xh + ae0, An + dAe[0]);
    gl_lds16(Xh + ae1, An + dAe[1]);
    gl_lds16(Wh + (oB0[0] + kf2), Bn + dB0[0]);
    gl_lds16(Wh + (oB0[1] + kf2), Bn + dB0[1]);
    gl_lds16(Wh + (oB1[0] + kf2), Bn + dB1[0]);
    gl_lds16(Wh + (oB1[1] + kf2), Bn + dB1[1]);
    gl_lds16(Xh + ao0, An + dAo[0]);
    gl_lds16(Xh + ao1, An + dAo[1]);
    read4(Ac, wmBase, 0, r, q, af);
    read4(Bc, wnBase, 0, r, q, bf0);
    BAR(); LGKM0();
    __builtin_amdgcn_s_setprio(1);
    mfma16(af, bf0, &acc[0]);
    __builtin_amdgcn_s_setprio(0);
    BAR();

    // P1: read A(mi0-3,kk32)+B(kk32); vmcnt(8) drains Ao(t) (issued P0(t-1),
    //     5 phases ago) while the 8 tile-(t+1) loads stay in flight.
    read4(Ac, wmBase, 32, r, q, af);
    read4(Bc, wnBase, 32, r, q, bf1);
    BAR(); LGKM0();
    __builtin_amdgcn_s_setprio(1);
    mfma16(af, bf1, &acc[0]);
    __builtin_amdgcn_s_setprio(0);
    VMW(8);
    BAR();

    // P2: read A(mi4-7,kk0) (Ao region, now safe), reuse bf0.
    read4(Ac, wmBase + 64, 0, r, q, af);
    BAR(); LGKM0();
    __builtin_amdgcn_s_setprio(1);
    mfma16(af, bf0, &acc[4]);
    __builtin_amdgcn_s_setprio(0);
    BAR();

    // P3: read A(mi4-7,kk32), reuse bf1; vmcnt(2) drains Ae/B0/B1(t+1)
    //     (issued 3.5 phases ago); Ao(t+1) keeps flying.
    read4(Ac, wmBase + 64, 32, r, q, af);
    BAR(); LGKM0();
    __builtin_amdgcn_s_setprio(1);
    mfma16(af, bf1, &acc[4]);
    __builtin_amdgcn_s_setprio(0);
    VMW(2);
    BAR();
  }

  // Tail tile t = NT-1 (buf 1): no staging; drain Ao(31) before P2 reads.
  {
    const f16* Ac = As[1];
    const f16* Bc = Bs[1];
    f16x8 af[4], bf0[4], bf1[4];
    read4(Ac, wmBase, 0, r, q, af);
    read4(Bc, wnBase, 0, r, q, bf0);
    BAR(); LGKM0();
    __builtin_amdgcn_s_setprio(1);
    mfma16(af, bf0, &acc[0]);
    __builtin_amdgcn_s_setprio(0);
    BAR();
    read4(Ac, wmBase, 32, r, q, af);
    read4(Bc, wnBase, 32, r, q, bf1);
    BAR(); LGKM0();
    __builtin_amdgcn_s_setprio(1);
    mfma16(af, bf1, &acc[0]);
    __builtin_amdgcn_s_setprio(0);
    VMW(0);
    BAR();
    read4(Ac, wmBase + 64, 0, r, q, af);
    BAR(); LGKM0();
    __builtin_amdgcn_s_setprio(1);
    mfma16(af, bf0, &acc[4]);
    __builtin_amdgcn_s_setprio(0);
    BAR();
    read4(Ac, wmBase + 64, 32, r, q, af);
    BAR(); LGKM0();
    __builtin_amdgcn_s_setprio(1);
    mfma16(af, bf1, &acc[4]);
    __builtin_amdgcn_s_setprio(0);
  }

  // Epilogue: C/D layout col=lane&15, row=q*4+reg. Gate uniform per block
  // (n0 256-aligned, gate regions 1024-aligned).
  const int gate = n0 >> 10;
  f16* gp_out = (gate == 0) ? Zg : ((gate == 1) ? Fg : Og);
#pragma unroll
  for (int ni = 0; ni < 4; ++ni) {
    const int gcol = n0 + wnBase + ni * 16 + r;
    const int h = gcol & 1023;
    const float bv = bias[gcol];
#pragma unroll
    for (int mi = 0; mi < 8; ++mi) {
#pragma unroll
      for (int reg = 0; reg < 4; ++reg) {
        const int grow = m0 + wmBase + mi * 16 + q * 4 + reg;
        const int s = grow >> 4, bb = grow & 15;
        const float y = acc[mi][ni][reg] + bv;
        float vv;
        if (gate == 0) vv = 2.f / (1.f + __expf(-2.f * y)) - 1.f;  // tanh
        else           vv = 1.f / (1.f + __expf(-y));              // sigmoid
        gp_out[(size_t)s * BH + bb * Hh + h] = (f16)vv;
      }
    }
  }
}

// ---- sequence-parallel scan (unchanged) ------------------------------------
__global__ __launch_bounds__(256, 4)
void chunk_reduce(const f16* __restrict__ Zg, const f16* __restrict__ Fg,
                  float* __restrict__ Apart, float* __restrict__ Bpart) {
  const int idx = blockIdx.x * 256 + threadIdx.x;
  const int q = idx & (NQ - 1);
  const int p = idx >> 13;
  const int base = p * CL;
  constexpr int U = 16;
  f16x2 zb[2][U], fb[2][U];
#pragma unroll
  for (int i = 0; i < U; ++i) {
    zb[0][i] = ((const f16x2*)(Zg + (size_t)(base + i) * BH))[q];
    fb[0][i] = ((const f16x2*)(Fg + (size_t)(base + i) * BH))[q];
  }
  float a0 = 1.f, a1 = 1.f, c0 = 0.f, c1 = 0.f;
  for (int t = 0; t < CL; t += 2 * U) {
#pragma unroll
    for (int i = 0; i < U; ++i) {
      zb[1][i] = ((const f16x2*)(Zg + (size_t)(base + t + U + i) * BH))[q];
      fb[1][i] = ((const f16x2*)(Fg + (size_t)(base + t + U + i) * BH))[q];
    }
#pragma unroll
    for (int i = 0; i < U; ++i) {
      const float f0 = (float)fb[0][i][0], f1 = (float)fb[0][i][1];
      const float z0 = (float)zb[0][i][0], z1 = (float)zb[0][i][1];
      c0 = fmaf(f0, z0 - c0, c0); c1 = fmaf(f1, z1 - c1, c1);
      a0 *= 1.f - f0; a1 *= 1.f - f1;
    }
    if (t + 2 * U < CL) {
#pragma unroll
      for (int i = 0; i < U; ++i) {
        zb[0][i] = ((const f16x2*)(Zg + (size_t)(base + t + 2 * U + i) * BH))[q];
        fb[0][i] = ((const f16x2*)(Fg + (size_t)(base + t + 2 * U + i) * BH))[q];
      }
    }
#pragma unroll
    for (int i = 0; i < U; ++i) {
      const float f0 = (float)fb[1][i][0], f1 = (float)fb[1][i][1];
      const float z0 = (float)zb[1][i][0], z1 = (float)zb[1][i][1];
      c0 = fmaf(f0, z0 - c0, c0); c1 = fmaf(f1, z1 - c1, c1);
      a0 *= 1.f - f0; a1 *= 1.f - f1;
    }
  }
  ((float2*)Apart)[(size_t)p * NQ + q] = make_float2(a0, a1);
  ((float2*)Bpart)[(size_t)p * NQ + q] = make_float2(c0, c1);
}

__global__ __launch_bounds__(256)
void chunk_scan(const float* __restrict__ Apart, const float* __restrict__ Bpart,
                const float* __restrict__ hidden, float* __restrict__ Cin,
                float* __restrict__ out) {
  const int q = blockIdx.x * 256 + threadIdx.x;  // 0..NQ-1
  float2 c = ((const float2*)hidden)[q];
#pragma unroll
  for (int p = 0; p < NCH; ++p) {
    ((float2*)Cin)[(size_t)p * NQ + q] = c;
    const float2 a = ((const float2*)Apart)[(size_t)p * NQ + q];
    const float2 b = ((const float2*)Bpart)[(size_t)p * NQ + q];
    c.x = fmaf(a.x, c.x, b.x);
    c.y = fmaf(a.y, c.y, b.y);
  }
  ((float2*)(out + (size_t)Ss * BH))[q] = c;  // c_last
}

__global__ __launch_bounds__(256, 4)
void chunk_apply(const f16* __restrict__ Zg, const f16* __restrict__ Fg,
                 const f16* __restrict__ Og, const float* __restrict__ Cin,
                 float* __restrict__ out) {
  const int idx = blockIdx.x * 256 + threadIdx.x;
  const int q = idx & (NQ - 1);
  const int p = idx >> 13;
  const int base = p * CL;
  constexpr int U = 16;
  f16x2 zb[2][U], fb[2][U], ob[2][U];
#pragma unroll
  for (int i = 0; i < U; ++i) {
    zb[0][i] = ((const f16x2*)(Zg + (size_t)(base + i) * BH))[q];
    fb[0][i] = ((const f16x2*)(Fg + (size_t)(base + i) * BH))[q];
    ob[0][i] = ((const f16x2*)(Og + (size_t)(base + i) * BH))[q];
  }
  float2 c = ((const float2*)Cin)[(size_t)p * NQ + q];
  for (int t = 0; t < CL; t += 2 * U) {
#pragma unroll
    for (int i = 0; i < U; ++i) {
      zb[1][i] = ((const f16x2*)(Zg + (size_t)(base + t + U + i) * BH))[q];
      fb[1][i] = ((const f16x2*)(Fg + (size_t)(base + t + U + i) * BH))[q];
      ob[1][i] = ((const f16x2*)(Og + (size_t)(base + t + U + i) * BH))[q];
    }
#pragma unroll
    for (int i = 0; i < U; ++i) {
      const float f0 = (float)fb[0][i][0], f1 = (float)fb[0][i][1];
      const float z0 = (float)zb[0][i][0], z1 = (float)zb[0][i][1];
      c.x = fmaf(f0, z0 - c.x, c.x); c.y = fmaf(f1, z1 - c.y, c.y);
      ((float2*)(out + (size_t)(base + t + i) * BH))[q] =
          make_float2((float)ob[0][i][0] * c.x, (float)ob[0][i][1] * c.y);
    }
    if (t + 2 * U < CL) {
#pragma unroll
      for (int i = 0; i < U; ++i) {
        zb[0][i] = ((const f16x2*)(Zg + (size_t)(base + t + 2 * U + i) * BH))[q];
        fb[0][i] = ((const f16x2*)(Fg + (size_t)(base + t + 2 * U + i) * BH))[q];
        ob[0][i] = ((const f16x2*)(Og + (size_t)(base + t + 2 * U + i) * BH))[q];
      }
    }
#pragma unroll
    for (int i = 0; i < U; ++i) {
      const float f0 = (float)fb[1][i][0], f1 = (float)fb[1][i][1];
      const float z0 = (float)zb[1][i][0], z1 = (float)zb[1][i][1];
      c.x = fmaf(f0, z0 - c.x, c.x); c.y = fmaf(f1, z1 - c.y, c.y);
      ((float2*)(out + (size_t)(base + t + U + i) * BH))[q] =
          make_float2((float)ob[1][i][0] * c.x, (float)ob[1][i][1] * c.y);
    }
  }
}

extern "C" void kernel_launch(void* const* d_in, const int* in_sizes, int n_in,
                              void* d_out, int out_size, void* d_ws, size_t ws_size,
                              hipStream_t stream) {
  const float* X      = (const float*)d_in[0];  // (B,S,D)
  const float* hidden = (const float*)d_in[1];  // (B,H)
  const float* W      = (const float*)d_in[2];  // (3H,2D)
  const float* bias   = (const float*)d_in[3];  // (3H)
  float* out = (float*)d_out;

  // ws layout:
  //   Wh   f16   12,582,912 B
  //   zero pad    4,096 B  (must sit directly before Xh: s==0 shifted reads)
  //   Xh   f16   67,108,864 B
  //   Zg/Fg/Og f16  67,108,864 B each
  //   Apart/Bpart/Cin fp32 1,048,576 B each
  char* ws = (char*)d_ws;
  f16* Wh   = (f16*)ws;
  f16* zpad = (f16*)(ws + 12582912);
  f16* Xh   = (f16*)(ws + 12582912 + 4096);
  f16* Zg   = (f16*)(ws + 12582912 + 4096 + 67108864);
  f16* Fg   = (f16*)(ws + 12582912 + 4096 + 2 * 67108864);
  f16* Og   = (f16*)(ws + 12582912 + 4096 + 3 * 67108864);
  float* Apart = (float*)(ws + 12582912 + 4096 + 4 * 67108864);
  float* Bpart = Apart + NCH * BH;
  float* Cin   = Bpart + NCH * BH;

  hipMemsetAsync(zpad, 0, 4096, stream);

  {
    int n4 = (Nn * Kk) / 4;
    cvt_f32_f16<<<(n4 + 255) / 256, 256, 0, stream>>>(W, Wh, n4);
  }
  {
    int n4 = (Bb * Ss * Dd) / 4;
    cvt_f32_f16<<<(n4 + 255) / 256, 256, 0, stream>>>(X, Xh, n4);
  }
  gemm_gates<<<dim3(1536), 512, 0, stream>>>(Xh, Wh, bias, Zg, Fg, Og);
  chunk_reduce<<<(NCH * NQ) / 256, 256, 0, stream>>>(Zg, Fg, Apart, Bpart);
  chunk_scan<<<NQ / 256, 256, 0, stream>>>(Apart, Bpart, hidden, Cin, out);
  chunk_apply<<<(NCH * NQ) / 256, 256, 0, stream>>>(Zg, Fg, Og, Cin, out);
}

// Round 7
// 742.687 us; speedup vs baseline: 1.1619x; 1.1619x over previous
//
#include <hip/hip_runtime.h>
#include <hip/hip_bf16.h>
#include <cstdint>
#include <cstddef>

// QRNN (window=2) fused: f16 MFMA GEMM for gates + epilogue activations +
// sequence-parallel diagonal-recurrence scan.
//
// R1: XOR-swizzled LDS (bank conflicts -> 0). GEMM 605->440us (963 TF).
// R2: 3-phase sequence-parallel scan (chunk reduce/scan/apply). Total 729us.
// R3-R5: two attempts at the 256^2 8-phase counted-vmcnt schedule BOTH
//     regressed (527us/35% and 597us/30% vs 428us/47%). Root cause unclear;
//     the window-gather A staging is an 8x128B scatter per gl_lds which
//     breaks the assumptions of the deep pipeline. REVERTED.
// R6: GEMM restored verbatim to the measured-best R0 128^2 kernel.
//     Scan vectorization: chunk_reduce/chunk_apply now process 4 chains/thread
//     (f16x4 8B loads, float4 16B stores; was f16x2 4B/8B). 65536 threads,
//     U=8 double-buffer keeps ~16 wave-loads in flight -> still BW-saturating.
//     chunk_scan and ws layout byte-identical to R0.
// R7/R8: resubmissions of R6 — rounds failed with GPUAcquisitionTimeout
//     (broker capacity), no measurement was taken.

typedef _Float16 f16;
typedef _Float16 f16x2 __attribute__((ext_vector_type(2)));
typedef _Float16 f16x4 __attribute__((ext_vector_type(4)));
typedef _Float16 f16x8 __attribute__((ext_vector_type(8)));
typedef float f32x4 __attribute__((ext_vector_type(4)));

#define Bb 16
#define Ss 2048
#define Dd 1024
#define Hh 1024
#define Nn (3 * Hh)   // 3072
#define Kk (2 * Dd)   // 2048
#define BH (Bb * Hh)  // 16384
#define NCH 16        // scan chunks
#define CL 128        // chunk length = Ss/NCH
#define NQ 8192       // chain pairs = BH/2 (phase-2 scan granularity)
#define NQ4 4096      // chain quads = BH/4 (reduce/apply granularity)

__device__ __forceinline__ void gl_lds16(const void* g, void* l) {
  __builtin_amdgcn_global_load_lds(
      (const __attribute__((address_space(1))) void*)g,
      (__attribute__((address_space(3))) void*)l, 16, 0, 0);
}

__global__ void cvt_f32_f16(const float* __restrict__ in, f16* __restrict__ out, int n4) {
  int i = blockIdx.x * blockDim.x + threadIdx.x;
  if (i < n4) {
    const float4 v = ((const float4*)in)[i];
    f16x4 h;
    h[0] = (f16)v.x; h[1] = (f16)v.y; h[2] = (f16)v.z; h[3] = (f16)v.w;
    ((f16x4*)out)[i] = h;
  }
}

// 128x128 tile, BK=64, 256 threads (4 waves, each 64x64 via 4x4 MFMA 16x16x32 f16).
// Measured: 428us, MfmaUtil 47%, 963 TF (m97-structure plateau).
__global__ __launch_bounds__(256, 4)
void gemm_gates(const f16* __restrict__ Xh,    // (B,S,D) f16
                const f16* __restrict__ Wh,    // (3H,2D) f16
                const float* __restrict__ bias,// (3H)
                const f16* __restrict__ zblk,  // >=256 B of zeros
                f16* __restrict__ Zg, f16* __restrict__ Fg, f16* __restrict__ Og) {
  __shared__ __align__(16) f16 As[128 * 64];
  __shared__ __align__(16) f16 Bs[128 * 64];

  const int tid  = threadIdx.x;
  const int wave = tid >> 6;
  const int lane = tid & 63;
  const int bn = blockIdx.x;   // 0..23
  const int bm = blockIdx.y;   // 0..255
  const int m0 = bm * 128;
  const int n0 = bn * 128;

  const int wm = (wave >> 1) * 64;
  const int wn = (wave & 1) * 64;
  const int r  = lane & 15;
  const int q  = lane >> 4;

  // Staging: per instr 8 rows x 64 k-elems. lane -> row = row0 + lane/8.
  // XOR swizzle: LDS position p (= lane&7) holds global segment p ^ (row&7);
  // row bases are 8-aligned so row&7 == lane>>3.
  const int srl  = lane >> 3;                    // row within 8-row group = row&7
  const int sseg = ((lane & 7) ^ srl) * 8;       // swizzled global k-offset (elems)

  int as_[4], ab_[4];
#pragma unroll
  for (int i = 0; i < 4; ++i) {
    int mrow = m0 + wave * 32 + i * 8 + srl;
    as_[i] = mrow >> 4;   // s
    ab_[i] = mrow & 15;   // b
  }

  f32x4 acc[4][4];
#pragma unroll
  for (int i = 0; i < 4; ++i)
#pragma unroll
    for (int j = 0; j < 4; ++j)
      acc[i][j] = {0.f, 0.f, 0.f, 0.f};

  for (int kt = 0; kt < 32; ++kt) {
    const int kf = kt * 64;
    __syncthreads();
    // stage A (gathered window-concat); sseg < 64 keeps each load within the
    // same 64-elem k-tile, so the kf-level branch stays valid under swizzle.
#pragma unroll
    for (int i = 0; i < 4; ++i) {
      const int row0 = wave * 32 + i * 8;
      const f16* gp;
      if (kf < 1024) {
        gp = Xh + (size_t)ab_[i] * (Ss * Dd) + as_[i] * Dd + kf + sseg;
      } else if (as_[i] > 0) {
        gp = Xh + (size_t)ab_[i] * (Ss * Dd) + (as_[i] - 1) * Dd + (kf - 1024) + sseg;
      } else {
        gp = zblk + sseg;
      }
      gl_lds16(gp, &As[row0 * 64]);
    }
    // stage B (weights, [n][k] row-major = B^T natural layout)
#pragma unroll
    for (int i = 0; i < 4; ++i) {
      const int row0 = wave * 32 + i * 8;
      const f16* gp = Wh + (size_t)(n0 + row0 + srl) * Kk + kf + sseg;
      gl_lds16(gp, &Bs[row0 * 64]);
    }
    __syncthreads();
#pragma unroll
    for (int kk = 0; kk < 64; kk += 32) {
      f16x8 af[4], bf[4];
#pragma unroll
      for (int mi = 0; mi < 4; ++mi) {
        const int row = wm + mi * 16 + r;
        const int seg = ((kk >> 3) + q) ^ (row & 7);
        af[mi] = *(const f16x8*)&As[row * 64 + seg * 8];
      }
#pragma unroll
      for (int ni = 0; ni < 4; ++ni) {
        const int row = wn + ni * 16 + r;
        const int seg = ((kk >> 3) + q) ^ (row & 7);
        bf[ni] = *(const f16x8*)&Bs[row * 64 + seg * 8];
      }
#pragma unroll
      for (int mi = 0; mi < 4; ++mi)
#pragma unroll
        for (int ni = 0; ni < 4; ++ni)
          acc[mi][ni] =
              __builtin_amdgcn_mfma_f32_16x16x32_f16(af[mi], bf[ni], acc[mi][ni], 0, 0, 0);
    }
  }

  // epilogue: C/D layout col=lane&15, row=q*4+reg. Gate uniform per block
  // (n0 is 128-aligned, gate regions 1024-aligned).
  const int gate = n0 >> 10;
  f16* gp_out = (gate == 0) ? Zg : ((gate == 1) ? Fg : Og);
#pragma unroll
  for (int ni = 0; ni < 4; ++ni) {
    const int gcol = n0 + wn + ni * 16 + r;
    const int h = gcol & 1023;
    const float bv = bias[gcol];
#pragma unroll
    for (int mi = 0; mi < 4; ++mi) {
#pragma unroll
      for (int reg = 0; reg < 4; ++reg) {
        const int grow = m0 + wm + mi * 16 + q * 4 + reg;
        const int s = grow >> 4, bb = grow & 15;
        const float y = acc[mi][ni][reg] + bv;
        float v;
        if (gate == 0) v = 2.f / (1.f + __expf(-2.f * y)) - 1.f;  // tanh
        else           v = 1.f / (1.f + __expf(-y));              // sigmoid
        gp_out[(size_t)s * BH + bb * Hh + h] = (f16)v;
      }
    }
  }
}

// ---- sequence-parallel scan ------------------------------------------------
// Phase 1: per (chunk p, chain-quad qq) compute A = prod(1-f), B = chunk scan
// from c=0. 16 x 4096 threads = 256 blocks; f16x4 8B loads, U=8 dbuf.
// Apart/Bpart layout: [p][BH] scalar f32 (byte-compatible with chunk_scan's
// float2 view and chunk_apply4's float4 view).
__global__ __launch_bounds__(256, 4)
void chunk_reduce4(const f16* __restrict__ Zg, const f16* __restrict__ Fg,
                   float* __restrict__ Apart, float* __restrict__ Bpart) {
  const int idx = blockIdx.x * 256 + threadIdx.x;
  const int qq = idx & (NQ4 - 1);
  const int p = idx >> 12;
  const int base = p * CL;
  constexpr int U = 8;
  f16x4 zb[2][U], fb[2][U];
#pragma unroll
  for (int i = 0; i < U; ++i) {
    zb[0][i] = ((const f16x4*)(Zg + (size_t)(base + i) * BH))[qq];
    fb[0][i] = ((const f16x4*)(Fg + (size_t)(base + i) * BH))[qq];
  }
  float a0 = 1.f, a1 = 1.f, a2 = 1.f, a3 = 1.f;
  float c0 = 0.f, c1 = 0.f, c2 = 0.f, c3 = 0.f;
  for (int t = 0; t < CL; t += 2 * U) {
#pragma unroll
    for (int i = 0; i < U; ++i) {
      zb[1][i] = ((const f16x4*)(Zg + (size_t)(base + t + U + i) * BH))[qq];
      fb[1][i] = ((const f16x4*)(Fg + (size_t)(base + t + U + i) * BH))[qq];
    }
#pragma unroll
    for (int i = 0; i < U; ++i) {
      const float f0 = (float)fb[0][i][0], f1 = (float)fb[0][i][1];
      const float f2 = (float)fb[0][i][2], f3 = (float)fb[0][i][3];
      const float z0 = (float)zb[0][i][0], z1 = (float)zb[0][i][1];
      const float z2 = (float)zb[0][i][2], z3 = (float)zb[0][i][3];
      c0 = fmaf(f0, z0 - c0, c0); c1 = fmaf(f1, z1 - c1, c1);
      c2 = fmaf(f2, z2 - c2, c2); c3 = fmaf(f3, z3 - c3, c3);
      a0 *= 1.f - f0; a1 *= 1.f - f1; a2 *= 1.f - f2; a3 *= 1.f - f3;
    }
    if (t + 2 * U < CL) {
#pragma unroll
      for (int i = 0; i < U; ++i) {
        zb[0][i] = ((const f16x4*)(Zg + (size_t)(base + t + 2 * U + i) * BH))[qq];
        fb[0][i] = ((const f16x4*)(Fg + (size_t)(base + t + 2 * U + i) * BH))[qq];
      }
    }
#pragma unroll
    for (int i = 0; i < U; ++i) {
      const float f0 = (float)fb[1][i][0], f1 = (float)fb[1][i][1];
      const float f2 = (float)fb[1][i][2], f3 = (float)fb[1][i][3];
      const float z0 = (float)zb[1][i][0], z1 = (float)zb[1][i][1];
      const float z2 = (float)zb[1][i][2], z3 = (float)zb[1][i][3];
      c0 = fmaf(f0, z0 - c0, c0); c1 = fmaf(f1, z1 - c1, c1);
      c2 = fmaf(f2, z2 - c2, c2); c3 = fmaf(f3, z3 - c3, c3);
      a0 *= 1.f - f0; a1 *= 1.f - f1; a2 *= 1.f - f2; a3 *= 1.f - f3;
    }
  }
  float4 av; av.x = a0; av.y = a1; av.z = a2; av.w = a3;
  float4 cv; cv.x = c0; cv.y = c1; cv.z = c2; cv.w = c3;
  ((float4*)(Apart + (size_t)p * BH))[qq] = av;
  ((float4*)(Bpart + (size_t)p * BH))[qq] = cv;
}

// Phase 2: scan the 16 chunk composites per chain; emit per-chunk entry state
// Cin[p] and c_last (= out's trailing BH floats). (Byte-identical to R0.)
__global__ __launch_bounds__(256)
void chunk_scan(const float* __restrict__ Apart, const float* __restrict__ Bpart,
                const float* __restrict__ hidden, float* __restrict__ Cin,
                float* __restrict__ out) {
  const int q = blockIdx.x * 256 + threadIdx.x;  // 0..NQ-1
  float2 c = ((const float2*)hidden)[q];
#pragma unroll
  for (int p = 0; p < NCH; ++p) {
    ((float2*)Cin)[(size_t)p * NQ + q] = c;
    const float2 a = ((const float2*)Apart)[(size_t)p * NQ + q];
    const float2 b = ((const float2*)Bpart)[(size_t)p * NQ + q];
    c.x = fmaf(a.x, c.x, b.x);
    c.y = fmaf(a.y, c.y, b.y);
  }
  ((float2*)(out + (size_t)Ss * BH))[q] = c;  // c_last
}

// Phase 3: replay each chunk from its entry state, apply output gate, store.
// 4 chains/thread: f16x4 8B loads, float4 16B stores.
__global__ __launch_bounds__(256, 4)
void chunk_apply4(const f16* __restrict__ Zg, const f16* __restrict__ Fg,
                  const f16* __restrict__ Og, const float* __restrict__ Cin,
                  float* __restrict__ out) {
  const int idx = blockIdx.x * 256 + threadIdx.x;
  const int qq = idx & (NQ4 - 1);
  const int p = idx >> 12;
  const int base = p * CL;
  constexpr int U = 8;
  f16x4 zb[2][U], fb[2][U], ob[2][U];
#pragma unroll
  for (int i = 0; i < U; ++i) {
    zb[0][i] = ((const f16x4*)(Zg + (size_t)(base + i) * BH))[qq];
    fb[0][i] = ((const f16x4*)(Fg + (size_t)(base + i) * BH))[qq];
    ob[0][i] = ((const f16x4*)(Og + (size_t)(base + i) * BH))[qq];
  }
  float4 c = ((const float4*)(Cin + (size_t)p * BH))[qq];
  for (int t = 0; t < CL; t += 2 * U) {
#pragma unroll
    for (int i = 0; i < U; ++i) {
      zb[1][i] = ((const f16x4*)(Zg + (size_t)(base + t + U + i) * BH))[qq];
      fb[1][i] = ((const f16x4*)(Fg + (size_t)(base + t + U + i) * BH))[qq];
      ob[1][i] = ((const f16x4*)(Og + (size_t)(base + t + U + i) * BH))[qq];
    }
#pragma unroll
    for (int i = 0; i < U; ++i) {
      const float f0 = (float)fb[0][i][0], f1 = (float)fb[0][i][1];
      const float f2 = (float)fb[0][i][2], f3 = (float)fb[0][i][3];
      const float z0 = (float)zb[0][i][0], z1 = (float)zb[0][i][1];
      const float z2 = (float)zb[0][i][2], z3 = (float)zb[0][i][3];
      c.x = fmaf(f0, z0 - c.x, c.x); c.y = fmaf(f1, z1 - c.y, c.y);
      c.z = fmaf(f2, z2 - c.z, c.z); c.w = fmaf(f3, z3 - c.w, c.w);
      float4 o;
      o.x = (float)ob[0][i][0] * c.x; o.y = (float)ob[0][i][1] * c.y;
      o.z = (float)ob[0][i][2] * c.z; o.w = (float)ob[0][i][3] * c.w;
      ((float4*)(out + (size_t)(base + t + i) * BH))[qq] = o;
    }
    if (t + 2 * U < CL) {
#pragma unroll
      for (int i = 0; i < U; ++i) {
        zb[0][i] = ((const f16x4*)(Zg + (size_t)(base + t + 2 * U + i) * BH))[qq];
        fb[0][i] = ((const f16x4*)(Fg + (size_t)(base + t + 2 * U + i) * BH))[qq];
        ob[0][i] = ((const f16x4*)(Og + (size_t)(base + t + 2 * U + i) * BH))[qq];
      }
    }
#pragma unroll
    for (int i = 0; i < U; ++i) {
      const float f0 = (float)fb[1][i][0], f1 = (float)fb[1][i][1];
      const float f2 = (float)fb[1][i][2], f3 = (float)fb[1][i][3];
      const float z0 = (float)zb[1][i][0], z1 = (float)zb[1][i][1];
      const float z2 = (float)zb[1][i][2], z3 = (float)zb[1][i][3];
      c.x = fmaf(f0, z0 - c.x, c.x); c.y = fmaf(f1, z1 - c.y, c.y);
      c.z = fmaf(f2, z2 - c.z, c.z); c.w = fmaf(f3, z3 - c.w, c.w);
      float4 o;
      o.x = (float)ob[1][i][0] * c.x; o.y = (float)ob[1][i][1] * c.y;
      o.z = (float)ob[1][i][2] * c.z; o.w = (float)ob[1][i][3] * c.w;
      ((float4*)(out + (size_t)(base + t + U + i) * BH))[qq] = o;
    }
  }
}

extern "C" void kernel_launch(void* const* d_in, const int* in_sizes, int n_in,
                              void* d_out, int out_size, void* d_ws, size_t ws_size,
                              hipStream_t stream) {
  const float* X      = (const float*)d_in[0];  // (B,S,D)
  const float* hidden = (const float*)d_in[1];  // (B,H)
  const float* W      = (const float*)d_in[2];  // (3H,2D)
  const float* bias   = (const float*)d_in[3];  // (3H)
  float* out = (float*)d_out;

  // ws layout (identical to R0):
  //   [0,256)        zero block for s==0 shifted reads
  //   Wh  f16        12,582,912 B
  //   Xh  f16        67,108,864 B
  //   Zg/Fg/Og f16   67,108,864 B each
  //   Apart/Bpart/Cin fp32 16*16384*4 = 1,048,576 B each
  char* ws = (char*)d_ws;
  f16* zblk = (f16*)ws;
  f16* Wh = (f16*)(ws + 256);
  f16* Xh = (f16*)(ws + 256 + 12582912);
  f16* Zg = (f16*)(ws + 256 + 12582912 + 67108864);
  f16* Fg = (f16*)(ws + 256 + 12582912 + 2 * 67108864);
  f16* Og = (f16*)(ws + 256 + 12582912 + 3 * 67108864);
  float* Apart = (float*)(ws + 256 + 12582912 + 4 * 67108864);
  float* Bpart = Apart + NCH * BH;
  float* Cin   = Bpart + NCH * BH;

  hipMemsetAsync(zblk, 0, 256, stream);

  {
    int n4 = (Nn * Kk) / 4;
    cvt_f32_f16<<<(n4 + 255) / 256, 256, 0, stream>>>(W, Wh, n4);
  }
  {
    int n4 = (Bb * Ss * Dd) / 4;
    cvt_f32_f16<<<(n4 + 255) / 256, 256, 0, stream>>>(X, Xh, n4);
  }
  gemm_gates<<<dim3(24, 256), 256, 0, stream>>>(Xh, Wh, bias, zblk, Zg, Fg, Og);
  chunk_reduce4<<<(NCH * NQ4) / 256, 256, 0, stream>>>(Zg, Fg, Apart, Bpart);
  chunk_scan<<<NQ / 256, 256, 0, stream>>>(Apart, Bpart, hidden, Cin, out);
  chunk_apply4<<<(NCH * NQ4) / 256, 256, 0, stream>>>(Zg, Fg, Og, Cin, out);
}

// Round 13
// 731.299 us; speedup vs baseline: 1.1800x; 1.0156x over previous
//
#include <hip/hip_runtime.h>
#include <hip/hip_bf16.h>
#include <cstdint>
#include <cstddef>

// QRNN (window=2) fused: f16 MFMA GEMM for gates + epilogue activations +
// sequence-parallel diagonal-recurrence scan.
//
// R1: XOR-swizzled LDS (bank conflicts -> 0). GEMM 605->440us (963 TF).
// R2: 3-phase sequence-parallel scan (chunk reduce/scan/apply). Total 729us.
// R3-R5: two attempts at the 256^2 8-phase counted-vmcnt schedule BOTH
//     regressed (527us/35% and 597us/30% vs 428us/47%). REVERTED; GEMM stays
//     on the m97-structure 128^2 plateau (session-dependent 428-464us).
// R6: scan vectorized to 4 chains/thread (f16x4 8B loads, float4 16B stores).
//     Measured: non-GEMM 301->278us. Shortfall vs prediction diagnosed as
//     occupancy: 256 blocks = 1 block/CU = 4 waves/CU for the streamers.
// R7: NCH 16->32 (CL 64): reduce/apply grids double to 512 blocks
//     (2 blocks/CU, 8 waves/CU). Nontemporal stores for the write-once `out`
//     stream in chunk_apply4. GEMM byte-identical to R0/R6.
// R8-R11: infrastructure failures (GPUAcquisitionTimeout x3, container x1).
// R12: COMPILE FAIL — __builtin_nontemporal_store rejects HIP float4
//     (HIP_vector_type struct, not a clang ext_vector).
// R13 (this): nontemporal stores go through ext_vector f32x4 instead of
//     float4. Identical bytes/layout; only the builtin's pointer type changes.

typedef _Float16 f16;
typedef _Float16 f16x2 __attribute__((ext_vector_type(2)));
typedef _Float16 f16x4 __attribute__((ext_vector_type(4)));
typedef _Float16 f16x8 __attribute__((ext_vector_type(8)));
typedef float f32x4 __attribute__((ext_vector_type(4)));

#define Bb 16
#define Ss 2048
#define Dd 1024
#define Hh 1024
#define Nn (3 * Hh)   // 3072
#define Kk (2 * Dd)   // 2048
#define BH (Bb * Hh)  // 16384
#define NCH 32        // scan chunks
#define CL 64         // chunk length = Ss/NCH
#define NQ 8192       // chain pairs = BH/2 (phase-2 scan granularity)
#define NQ4 4096      // chain quads = BH/4 (reduce/apply granularity)

__device__ __forceinline__ void gl_lds16(const void* g, void* l) {
  __builtin_amdgcn_global_load_lds(
      (const __attribute__((address_space(1))) void*)g,
      (__attribute__((address_space(3))) void*)l, 16, 0, 0);
}

__global__ void cvt_f32_f16(const float* __restrict__ in, f16* __restrict__ out, int n4) {
  int i = blockIdx.x * blockDim.x + threadIdx.x;
  if (i < n4) {
    const float4 v = ((const float4*)in)[i];
    f16x4 h;
    h[0] = (f16)v.x; h[1] = (f16)v.y; h[2] = (f16)v.z; h[3] = (f16)v.w;
    ((f16x4*)out)[i] = h;
  }
}

// 128x128 tile, BK=64, 256 threads (4 waves, each 64x64 via 4x4 MFMA 16x16x32 f16).
// Measured: 428-464us (session noise), MfmaUtil 43-47% (m97-structure plateau).
__global__ __launch_bounds__(256, 4)
void gemm_gates(const f16* __restrict__ Xh,    // (B,S,D) f16
                const f16* __restrict__ Wh,    // (3H,2D) f16
                const float* __restrict__ bias,// (3H)
                const f16* __restrict__ zblk,  // >=256 B of zeros
                f16* __restrict__ Zg, f16* __restrict__ Fg, f16* __restrict__ Og) {
  __shared__ __align__(16) f16 As[128 * 64];
  __shared__ __align__(16) f16 Bs[128 * 64];

  const int tid  = threadIdx.x;
  const int wave = tid >> 6;
  const int lane = tid & 63;
  const int bn = blockIdx.x;   // 0..23
  const int bm = blockIdx.y;   // 0..255
  const int m0 = bm * 128;
  const int n0 = bn * 128;

  const int wm = (wave >> 1) * 64;
  const int wn = (wave & 1) * 64;
  const int r  = lane & 15;
  const int q  = lane >> 4;

  // Staging: per instr 8 rows x 64 k-elems. lane -> row = row0 + lane/8.
  // XOR swizzle: LDS position p (= lane&7) holds global segment p ^ (row&7);
  // row bases are 8-aligned so row&7 == lane>>3.
  const int srl  = lane >> 3;                    // row within 8-row group = row&7
  const int sseg = ((lane & 7) ^ srl) * 8;       // swizzled global k-offset (elems)

  int as_[4], ab_[4];
#pragma unroll
  for (int i = 0; i < 4; ++i) {
    int mrow = m0 + wave * 32 + i * 8 + srl;
    as_[i] = mrow >> 4;   // s
    ab_[i] = mrow & 15;   // b
  }

  f32x4 acc[4][4];
#pragma unroll
  for (int i = 0; i < 4; ++i)
#pragma unroll
    for (int j = 0; j < 4; ++j)
      acc[i][j] = {0.f, 0.f, 0.f, 0.f};

  for (int kt = 0; kt < 32; ++kt) {
    const int kf = kt * 64;
    __syncthreads();
    // stage A (gathered window-concat); sseg < 64 keeps each load within the
    // same 64-elem k-tile, so the kf-level branch stays valid under swizzle.
#pragma unroll
    for (int i = 0; i < 4; ++i) {
      const int row0 = wave * 32 + i * 8;
      const f16* gp;
      if (kf < 1024) {
        gp = Xh + (size_t)ab_[i] * (Ss * Dd) + as_[i] * Dd + kf + sseg;
      } else if (as_[i] > 0) {
        gp = Xh + (size_t)ab_[i] * (Ss * Dd) + (as_[i] - 1) * Dd + (kf - 1024) + sseg;
      } else {
        gp = zblk + sseg;
      }
      gl_lds16(gp, &As[row0 * 64]);
    }
    // stage B (weights, [n][k] row-major = B^T natural layout)
#pragma unroll
    for (int i = 0; i < 4; ++i) {
      const int row0 = wave * 32 + i * 8;
      const f16* gp = Wh + (size_t)(n0 + row0 + srl) * Kk + kf + sseg;
      gl_lds16(gp, &Bs[row0 * 64]);
    }
    __syncthreads();
#pragma unroll
    for (int kk = 0; kk < 64; kk += 32) {
      f16x8 af[4], bf[4];
#pragma unroll
      for (int mi = 0; mi < 4; ++mi) {
        const int row = wm + mi * 16 + r;
        const int seg = ((kk >> 3) + q) ^ (row & 7);
        af[mi] = *(const f16x8*)&As[row * 64 + seg * 8];
      }
#pragma unroll
      for (int ni = 0; ni < 4; ++ni) {
        const int row = wn + ni * 16 + r;
        const int seg = ((kk >> 3) + q) ^ (row & 7);
        bf[ni] = *(const f16x8*)&Bs[row * 64 + seg * 8];
      }
#pragma unroll
      for (int mi = 0; mi < 4; ++mi)
#pragma unroll
        for (int ni = 0; ni < 4; ++ni)
          acc[mi][ni] =
              __builtin_amdgcn_mfma_f32_16x16x32_f16(af[mi], bf[ni], acc[mi][ni], 0, 0, 0);
    }
  }

  // epilogue: C/D layout col=lane&15, row=q*4+reg. Gate uniform per block
  // (n0 is 128-aligned, gate regions 1024-aligned).
  const int gate = n0 >> 10;
  f16* gp_out = (gate == 0) ? Zg : ((gate == 1) ? Fg : Og);
#pragma unroll
  for (int ni = 0; ni < 4; ++ni) {
    const int gcol = n0 + wn + ni * 16 + r;
    const int h = gcol & 1023;
    const float bv = bias[gcol];
#pragma unroll
    for (int mi = 0; mi < 4; ++mi) {
#pragma unroll
      for (int reg = 0; reg < 4; ++reg) {
        const int grow = m0 + wm + mi * 16 + q * 4 + reg;
        const int s = grow >> 4, bb = grow & 15;
        const float y = acc[mi][ni][reg] + bv;
        float v;
        if (gate == 0) v = 2.f / (1.f + __expf(-2.f * y)) - 1.f;  // tanh
        else           v = 1.f / (1.f + __expf(-y));              // sigmoid
        gp_out[(size_t)s * BH + bb * Hh + h] = (f16)v;
      }
    }
  }
}

// ---- sequence-parallel scan ------------------------------------------------
// Phase 1: per (chunk p, chain-quad qq) compute A = prod(1-f), B = chunk scan
// from c=0. 32 x 4096 threads = 512 blocks (2/CU, 8 waves/CU); f16x4 8B loads,
// U=8 dbuf. Apart/Bpart layout: [p][BH] scalar f32 (byte-compatible with
// chunk_scan's float2 view and chunk_apply4's f32x4 view).
__global__ __launch_bounds__(256, 4)
void chunk_reduce4(const f16* __restrict__ Zg, const f16* __restrict__ Fg,
                   float* __restrict__ Apart, float* __restrict__ Bpart) {
  const int idx = blockIdx.x * 256 + threadIdx.x;
  const int qq = idx & (NQ4 - 1);
  const int p = idx >> 12;
  const int base = p * CL;
  constexpr int U = 8;
  f16x4 zb[2][U], fb[2][U];
#pragma unroll
  for (int i = 0; i < U; ++i) {
    zb[0][i] = ((const f16x4*)(Zg + (size_t)(base + i) * BH))[qq];
    fb[0][i] = ((const f16x4*)(Fg + (size_t)(base + i) * BH))[qq];
  }
  float a0 = 1.f, a1 = 1.f, a2 = 1.f, a3 = 1.f;
  float c0 = 0.f, c1 = 0.f, c2 = 0.f, c3 = 0.f;
  for (int t = 0; t < CL; t += 2 * U) {
#pragma unroll
    for (int i = 0; i < U; ++i) {
      zb[1][i] = ((const f16x4*)(Zg + (size_t)(base + t + U + i) * BH))[qq];
      fb[1][i] = ((const f16x4*)(Fg + (size_t)(base + t + U + i) * BH))[qq];
    }
#pragma unroll
    for (int i = 0; i < U; ++i) {
      const float f0 = (float)fb[0][i][0], f1 = (float)fb[0][i][1];
      const float f2 = (float)fb[0][i][2], f3 = (float)fb[0][i][3];
      const float z0 = (float)zb[0][i][0], z1 = (float)zb[0][i][1];
      const float z2 = (float)zb[0][i][2], z3 = (float)zb[0][i][3];
      c0 = fmaf(f0, z0 - c0, c0); c1 = fmaf(f1, z1 - c1, c1);
      c2 = fmaf(f2, z2 - c2, c2); c3 = fmaf(f3, z3 - c3, c3);
      a0 *= 1.f - f0; a1 *= 1.f - f1; a2 *= 1.f - f2; a3 *= 1.f - f3;
    }
    if (t + 2 * U < CL) {
#pragma unroll
      for (int i = 0; i < U; ++i) {
        zb[0][i] = ((const f16x4*)(Zg + (size_t)(base + t + 2 * U + i) * BH))[qq];
        fb[0][i] = ((const f16x4*)(Fg + (size_t)(base + t + 2 * U + i) * BH))[qq];
      }
    }
#pragma unroll
    for (int i = 0; i < U; ++i) {
      const float f0 = (float)fb[1][i][0], f1 = (float)fb[1][i][1];
      const float f2 = (float)fb[1][i][2], f3 = (float)fb[1][i][3];
      const float z0 = (float)zb[1][i][0], z1 = (float)zb[1][i][1];
      const float z2 = (float)zb[1][i][2], z3 = (float)zb[1][i][3];
      c0 = fmaf(f0, z0 - c0, c0); c1 = fmaf(f1, z1 - c1, c1);
      c2 = fmaf(f2, z2 - c2, c2); c3 = fmaf(f3, z3 - c3, c3);
      a0 *= 1.f - f0; a1 *= 1.f - f1; a2 *= 1.f - f2; a3 *= 1.f - f3;
    }
  }
  f32x4 av; av[0] = a0; av[1] = a1; av[2] = a2; av[3] = a3;
  f32x4 cv; cv[0] = c0; cv[1] = c1; cv[2] = c2; cv[3] = c3;
  ((f32x4*)(Apart + (size_t)p * BH))[qq] = av;
  ((f32x4*)(Bpart + (size_t)p * BH))[qq] = cv;
}

// Phase 2: scan the 32 chunk composites per chain; emit per-chunk entry state
// Cin[p] and c_last (= out's trailing BH floats).
__global__ __launch_bounds__(256)
void chunk_scan(const float* __restrict__ Apart, const float* __restrict__ Bpart,
                const float* __restrict__ hidden, float* __restrict__ Cin,
                float* __restrict__ out) {
  const int q = blockIdx.x * 256 + threadIdx.x;  // 0..NQ-1
  float2 c = ((const float2*)hidden)[q];
#pragma unroll
  for (int p = 0; p < NCH; ++p) {
    ((float2*)Cin)[(size_t)p * NQ + q] = c;
    const float2 a = ((const float2*)Apart)[(size_t)p * NQ + q];
    const float2 b = ((const float2*)Bpart)[(size_t)p * NQ + q];
    c.x = fmaf(a.x, c.x, b.x);
    c.y = fmaf(a.y, c.y, b.y);
  }
  ((float2*)(out + (size_t)Ss * BH))[q] = c;  // c_last
}

// Phase 3: replay each chunk from its entry state, apply output gate, store.
// 4 chains/thread: f16x4 8B loads, nontemporal f32x4 16B stores (write-once
// stream; keep L2 for the gate reads). ext_vector f32x4, not HIP float4 —
// __builtin_nontemporal_store requires a native clang vector type (R12 fail).
__global__ __launch_bounds__(256, 4)
void chunk_apply4(const f16* __restrict__ Zg, const f16* __restrict__ Fg,
                  const f16* __restrict__ Og, const float* __restrict__ Cin,
                  float* __restrict__ out) {
  const int idx = blockIdx.x * 256 + threadIdx.x;
  const int qq = idx & (NQ4 - 1);
  const int p = idx >> 12;
  const int base = p * CL;
  constexpr int U = 8;
  f16x4 zb[2][U], fb[2][U], ob[2][U];
#pragma unroll
  for (int i = 0; i < U; ++i) {
    zb[0][i] = ((const f16x4*)(Zg + (size_t)(base + i) * BH))[qq];
    fb[0][i] = ((const f16x4*)(Fg + (size_t)(base + i) * BH))[qq];
    ob[0][i] = ((const f16x4*)(Og + (size_t)(base + i) * BH))[qq];
  }
  f32x4 c = ((const f32x4*)(Cin + (size_t)p * BH))[qq];
  for (int t = 0; t < CL; t += 2 * U) {
#pragma unroll
    for (int i = 0; i < U; ++i) {
      zb[1][i] = ((const f16x4*)(Zg + (size_t)(base + t + U + i) * BH))[qq];
      fb[1][i] = ((const f16x4*)(Fg + (size_t)(base + t + U + i) * BH))[qq];
      ob[1][i] = ((const f16x4*)(Og + (size_t)(base + t + U + i) * BH))[qq];
    }
#pragma unroll
    for (int i = 0; i < U; ++i) {
      const float f0 = (float)fb[0][i][0], f1 = (float)fb[0][i][1];
      const float f2 = (float)fb[0][i][2], f3 = (float)fb[0][i][3];
      const float z0 = (float)zb[0][i][0], z1 = (float)zb[0][i][1];
      const float z2 = (float)zb[0][i][2], z3 = (float)zb[0][i][3];
      c[0] = fmaf(f0, z0 - c[0], c[0]); c[1] = fmaf(f1, z1 - c[1], c[1]);
      c[2] = fmaf(f2, z2 - c[2], c[2]); c[3] = fmaf(f3, z3 - c[3], c[3]);
      f32x4 o;
      o[0] = (float)ob[0][i][0] * c[0]; o[1] = (float)ob[0][i][1] * c[1];
      o[2] = (float)ob[0][i][2] * c[2]; o[3] = (float)ob[0][i][3] * c[3];
      __builtin_nontemporal_store(o, (f32x4*)(out + (size_t)(base + t + i) * BH) + qq);
    }
    if (t + 2 * U < CL) {
#pragma unroll
      for (int i = 0; i < U; ++i) {
        zb[0][i] = ((const f16x4*)(Zg + (size_t)(base + t + 2 * U + i) * BH))[qq];
        fb[0][i] = ((const f16x4*)(Fg + (size_t)(base + t + 2 * U + i) * BH))[qq];
        ob[0][i] = ((const f16x4*)(Og + (size_t)(base + t + 2 * U + i) * BH))[qq];
      }
    }
#pragma unroll
    for (int i = 0; i < U; ++i) {
      const float f0 = (float)fb[1][i][0], f1 = (float)fb[1][i][1];
      const float f2 = (float)fb[1][i][2], f3 = (float)fb[1][i][3];
      const float z0 = (float)zb[1][i][0], z1 = (float)zb[1][i][1];
      const float z2 = (float)zb[1][i][2], z3 = (float)zb[1][i][3];
      c[0] = fmaf(f0, z0 - c[0], c[0]); c[1] = fmaf(f1, z1 - c[1], c[1]);
      c[2] = fmaf(f2, z2 - c[2], c[2]); c[3] = fmaf(f3, z3 - c[3], c[3]);
      f32x4 o;
      o[0] = (float)ob[1][i][0] * c[0]; o[1] = (float)ob[1][i][1] * c[1];
      o[2] = (float)ob[1][i][2] * c[2]; o[3] = (float)ob[1][i][3] * c[3];
      __builtin_nontemporal_store(o, (f32x4*)(out + (size_t)(base + t + U + i) * BH) + qq);
    }
  }
}

extern "C" void kernel_launch(void* const* d_in, const int* in_sizes, int n_in,
                              void* d_out, int out_size, void* d_ws, size_t ws_size,
                              hipStream_t stream) {
  const float* X      = (const float*)d_in[0];  // (B,S,D)
  const float* hidden = (const float*)d_in[1];  // (B,H)
  const float* W      = (const float*)d_in[2];  // (3H,2D)
  const float* bias   = (const float*)d_in[3];  // (3H)
  float* out = (float*)d_out;

  // ws layout:
  //   [0,256)        zero block for s==0 shifted reads
  //   Wh  f16        12,582,912 B
  //   Xh  f16        67,108,864 B
  //   Zg/Fg/Og f16   67,108,864 B each
  //   Apart/Bpart/Cin fp32 32*16384*4 = 2,097,152 B each
  char* ws = (char*)d_ws;
  f16* zblk = (f16*)ws;
  f16* Wh = (f16*)(ws + 256);
  f16* Xh = (f16*)(ws + 256 + 12582912);
  f16* Zg = (f16*)(ws + 256 + 12582912 + 67108864);
  f16* Fg = (f16*)(ws + 256 + 12582912 + 2 * 67108864);
  f16* Og = (f16*)(ws + 256 + 12582912 + 3 * 67108864);
  float* Apart = (float*)(ws + 256 + 12582912 + 4 * 67108864);
  float* Bpart = Apart + NCH * BH;
  float* Cin   = Bpart + NCH * BH;

  (void)hipMemsetAsync(zblk, 0, 256, stream);

  {
    int n4 = (Nn * Kk) / 4;
    cvt_f32_f16<<<(n4 + 255) / 256, 256, 0, stream>>>(W, Wh, n4);
  }
  {
    int n4 = (Bb * Ss * Dd) / 4;
    cvt_f32_f16<<<(n4 + 255) / 256, 256, 0, stream>>>(X, Xh, n4);
  }
  gemm_gates<<<dim3(24, 256), 256, 0, stream>>>(Xh, Wh, bias, zblk, Zg, Fg, Og);
  chunk_reduce4<<<(NCH * NQ4) / 256, 256, 0, stream>>>(Zg, Fg, Apart, Bpart);
  chunk_scan<<<NQ / 256, 256, 0, stream>>>(Apart, Bpart, hidden, Cin, out);
  chunk_apply4<<<(NCH * NQ4) / 256, 256, 0, stream>>>(Zg, Fg, Og, Cin, out);
}